// Round 7
// baseline (415.368 us; speedup 1.0000x reference)
//
#include <hip/hip_runtime.h>

// Forecaster: B=64, S=1024, F=64, H=128. N = B*S = 65536 independent instances.
// R17: cross the 64-VGPR occupancy bucket. R15/R16 post-mortem: LDS cut and
// 2-deep prefetch both null (ring never materialized: VGPR 80->84 not +32,
// compiler serialized it). Model: ~45% of SIMD time neither pipe issues;
// 2 wgs/CU = 2 phase-streams convoy (epis together -> MFMA idle; gemms
// together -> VALU idle). Residency is pinned by the VGPR bucket (m69:
// waves/SIMD step at <=64 / <=128; VGPR 84 -> 4 waves/SIMD).
// Changes vs R16:
//  1. 32-row wgs (grid 2048, still 512 thr / 8 waves): mt=2 -> acc 64->32,
//     cc 16->8. Per-thread epi VALU halves, totals unchanged.
//  2. Revert to 1-deep bq prefetch (R14-equal perf, fewer live regs).
//  3. __launch_bounds__(512, 8): VGPR cap 64 -> 8 waves/SIMD -> 4 wgs/CU
//     (32 waves, 4 phase-streams). Bounded clamp use: est demand ~60-75
//     (R12's disaster was cap 64 vs demand ~150). ABORT next round if
//     WRITE_SIZE > 4MB (spill) or dur regresses.
//  4. LDS 24576/wg (3 x [32][256B] swizzled tiles; A0 aliases H2s).
// Kept: lgkm-only barriers; bias as MFMA C at kc=0; swizzled H tiles;
// setprio; 1-tile wgs; prep kernel and weight pack unchanged (8 waves/wg).

typedef _Float16 half8 __attribute__((ext_vector_type(8)));
typedef _Float16 half4_t __attribute__((ext_vector_type(4)));
typedef float f32x4 __attribute__((ext_vector_type(4)));

#define L2E  1.4426950408889634f
#define L2E2 2.8853900817779268f

#define WP_WIH0 0
#define WP_WHH0 32768
#define WP_WIH1 98304
#define WP_WHH1 163840
#define WS_BIAS0 458752            // bytes
#define WS_BIAS1 (458752 + 2048)
#define WS_MUG2  (458752 + 4096)

// ---------------- merged prep kernel (unchanged) ----------------------------
__global__ void prep_kernel(const float* __restrict__ Wih0,
                            const float* __restrict__ Whh0,
                            const float* __restrict__ Wih1,
                            const float* __restrict__ Whh1,
                            const float* __restrict__ bih0,
                            const float* __restrict__ bhh0,
                            const float* __restrict__ bih1,
                            const float* __restrict__ bhh1,
                            const float* __restrict__ mu,
                            _Float16* __restrict__ Wp,
                            float* __restrict__ bias0f,
                            float* __restrict__ bias1f,
                            float* __restrict__ mu_g2)
{
    int blk = blockIdx.x;
    if (blk >= 113) {                       // ---- mu_g2 part
        int o = (blk - 113) * 256 + threadIdx.x;   // 0..32767
        int b = o >> 9;
        int n = o & 511;
        float s = bih0[n] + bhh0[n];
        const float* m = mu + b * 64;
        const float* wrow = Wih0 + n * 64;
        #pragma unroll 8
        for (int k = 0; k < 64; ++k) s += m[k] * wrow[k];
        float scale = ((n >> 7) == 2) ? L2E2 : L2E;
        mu_g2[o] = s * scale;
        return;
    }
    if (blk == 112) {                       // ---- bias part
        int i = threadIdx.x;
        float sc_hi = (i < 128) ? L2E2 : L2E;
        bias0f[i]       = (bih0[i]       + bhh0[i])       * L2E;
        bias0f[i + 256] = (bih0[i + 256] + bhh0[i + 256]) * sc_hi;
        bias1f[i]       = (bih1[i]       + bhh1[i])       * L2E;
        bias1f[i + 256] = (bih1[i + 256] + bhh1[i + 256]) * sc_hi;
        return;
    }
    // ---- weight pack: [nt][kc][lane][8], c=lane&15 -> n=nt*16+c,
    //      q=lane>>4 -> k = kc*32 + q*8 .. +8  (scaled by gate)
    int gidx = blk * 256 + threadIdx.x;     // 0..28671 groups of 8 halfs
    const float* src; int KC, Kw, local;
    if (gidx < 4096)       { src = Wih0; KC = 2; Kw = 64;  local = gidx; }
    else if (gidx < 12288) { src = Whh0; KC = 4; Kw = 128; local = gidx - 4096; }
    else if (gidx < 20480) { src = Wih1; KC = 4; Kw = 128; local = gidx - 12288; }
    else                   { src = Whh1; KC = 4; Kw = 128; local = gidx - 20480; }
    int lane = local & 63;
    int tmp  = local >> 6;
    int kc   = tmp % KC;
    int nt   = tmp / KC;
    int n  = nt * 16 + (lane & 15);
    int k0 = kc * 32 + (lane >> 4) * 8;
    float scale = ((n >> 7) == 2) ? L2E2 : L2E;
    const float* s = src + n * Kw + k0;
    half8 hv;
    #pragma unroll
    for (int j = 0; j < 8; ++j) hv[j] = (_Float16)(s[j] * scale);
    *(half8*)(Wp + (size_t)gidx * 8) = hv;
}

// ---------------- bare-metal gate math -------------------------------------
__device__ __forceinline__ float sig2(float a) {
    return __builtin_amdgcn_rcpf(1.0f + __builtin_amdgcn_exp2f(-a));
}
__device__ __forceinline__ float tanh2(float a) {
    return fmaf(-2.0f, __builtin_amdgcn_rcpf(1.0f + __builtin_amdgcn_exp2f(a)), 1.0f);
}

// Swizzled byte offset into a [32 rows][256B] H tile (involution; same on
// write and read).
__device__ __forceinline__ int swz(int row, int col) {
    return (row << 8) + (col ^ ((row & 7) << 4));
}

// lgkm-only barrier: orders LDS writes across the wg WITHOUT draining vmcnt,
// so prefetched global weight loads stay in flight across it (T3/T4).
__device__ __forceinline__ void lds_barrier() {
    asm volatile("s_waitcnt lgkmcnt(0)" ::: "memory");
    __builtin_amdgcn_s_barrier();
    asm volatile("" ::: "memory");
}

__device__ __forceinline__ void load_bq(half8 bq[4], const _Float16* __restrict__ Wq,
                                        int KC, int kc, int w, int lane)
{
    #pragma unroll
    for (int g = 0; g < 4; ++g)
        bq[g] = *(const half8*)(Wq + (((g * 8 + w) * KC + kc) * 64 + lane) * 8);
}

template<int SRC>   // 0 = A0 (stride 72 halfs), 1 = swizzled H tile
__device__ __forceinline__ void load_a(half8 a[2], const char* base, int kc, int c, int q)
{
    #pragma unroll
    for (int mt = 0; mt < 2; ++mt) {
        if (SRC == 0)
            a[mt] = *(const half8*)((const _Float16*)base + (mt * 16 + c) * 72 + kc * 32 + q * 8);
        else
            a[mt] = *(const half8*)(base + swz(mt * 16 + c, kc * 64 + q * 16));
    }
}

// One gemm stage with 1-deep bq double-buffer (R14 design, mt=2). On entry
// bqc holds THIS stage's kc=0 weights; on exit (PF) the NEXT stage's kc=0.
// FIRST: bv[g] is the MFMA C operand at kc=0 (bias init without v_movs).
template<int KC, int SRC, bool PF, bool FIRST>
__device__ __forceinline__ void gemm_pf(const _Float16* __restrict__ Wq,
                                        const char* Abase,
                                        const _Float16* __restrict__ Wnext, int KCnext,
                                        half8 bqc[4], const f32x4 bv[4],
                                        int w, int lane, f32x4 acc[2][4])
{
    const int c = lane & 15, q = lane >> 4;
    #pragma unroll
    for (int kc = 0; kc < KC; ++kc) {
        half8 bqn[4];
        if (kc + 1 < KC)  load_bq(bqn, Wq, KC, kc + 1, w, lane);
        else if (PF)      load_bq(bqn, Wnext, KCnext, 0, w, lane);
        half8 a[2];
        load_a<SRC>(a, Abase, kc, c, q);
        __builtin_amdgcn_s_setprio(1);
        #pragma unroll
        for (int mt = 0; mt < 2; ++mt)
            #pragma unroll
            for (int g = 0; g < 4; ++g) {
                f32x4 cin = (FIRST && kc == 0) ? bv[g] : acc[mt][g];
                acc[mt][g] = __builtin_amdgcn_mfma_f32_16x16x32_f16(bqc[g], a[mt], cin, 0, 0, 0);
            }
        __builtin_amdgcn_s_setprio(0);
        if (kc + 1 < KC || PF) {
            #pragma unroll
            for (int g = 0; g < 4; ++g) bqc[g] = bqn[g];
        }
    }
}

__global__ __launch_bounds__(512, 8) void lstm_main(
    const float* __restrict__ x, const _Float16* __restrict__ Wp_in,
    const float* __restrict__ bias0f_in, const float* __restrict__ bias1f_in,
    const float* __restrict__ mu_g2_in, const float* __restrict__ fc_w_in,
    const float* __restrict__ fc_b_in, float* __restrict__ out)
{
    // LDS 24576 B (4 wg/CU = 98.3 KB <= 160):
    //  [0, 8192)        H1s   (swizzled [32][256B])
    //  [8192, 16384)    H2s   -- ALSO hosts A0 (32 x 72 halfs = 4608 B):
    //                      A0 dead at S1-barrier (lgkmcnt(0) drains its
    //                      ds_reads); H2s first written in epi2 after it.
    //  [16384, 24576)   H11s
    __shared__ __align__(16) char smem[24576];
    char* H1s  = smem;
    char* H2s  = smem + 8192;
    char* H11s = smem + 16384;
    _Float16* A0 = (_Float16*)(smem + 8192);     // alias of H2s region

    const int t = threadIdx.x;
    const int w = t >> 6, lane = t & 63, c = lane & 15, q = lane >> 4;
    const int wg = blockIdx.x;                   // 2048 wgs x 32 rows
    const int b = wg >> 5;                       // 32 wgs (1024 rows) per batch
    const int bq_idx = w * 4 + q;                // float4 index of (w,q) slice

    // ---- prefetch S1 kc=0 weights with maximum lead -----------------------
    half8 bqc[4];
    load_bq(bqc, Wp_in + WP_WIH0, 2, 0, w, lane);

    // ---- preamble: stage x tile into A0 (t<256, coalesced); init out rows -
    {
        if (t < 256) {
            const float* xp = x + (size_t)wg * 2048 + t * 8;
            float4 u0 = ((const float4*)xp)[0];
            float4 u1 = ((const float4*)xp)[1];
            half8 hv;
            hv[0] = (_Float16)u0.x; hv[1] = (_Float16)u0.y;
            hv[2] = (_Float16)u0.z; hv[3] = (_Float16)u0.w;
            hv[4] = (_Float16)u1.x; hv[5] = (_Float16)u1.y;
            hv[6] = (_Float16)u1.z; hv[7] = (_Float16)u1.w;
            *(half8*)(A0 + (t >> 3) * 72 + (t & 7) * 8) = hv;
        } else if (t < 288) {
            out[(size_t)wg * 32 + (t - 256)] = fc_b_in[0];
        }
    }
    lds_barrier();   // A0 visible (lgkm); weight prefetch still in flight

    f32x4 acc[2][4];
    float cc[2][4];

    // ---- S1: layer0 step1 (A from A0; bias0 as MFMA C) --------------------
    {
        f32x4 bv[4];
        {
            const float* bias0f = bias0f_in; asm volatile("" : "+s"(bias0f));
            #pragma unroll
            for (int g = 0; g < 4; ++g)
                bv[g] = ((const f32x4*)bias0f)[g * 32 + bq_idx];
        }
        gemm_pf<2, 0, true, true>(Wp_in + WP_WIH0, (const char*)A0,
                                  Wp_in + WP_WHH0, 4, bqc, bv, w, lane, acc);
    }
    #pragma unroll
    for (int mt = 0; mt < 2; ++mt) {
        half4_t hv;
        #pragma unroll
        for (int r = 0; r < 4; ++r) {
            float c1 = sig2(acc[mt][0][r]) * tanh2(acc[mt][2][r]);
            cc[mt][r] = c1;
            hv[r] = (_Float16)(sig2(acc[mt][3][r]) * tanh2(c1 * L2E2));
        }
        *(half4_t*)(H1s + swz(mt * 16 + c, w * 32 + q * 8)) = hv;
    }
    lds_barrier();   // [S1-barrier] H1s ready; A0 dead; Whh0 kc=0 in flight

    // ---- S2: layer0 step2 (A from H1s; mu_g2 as MFMA C) -------------------
    {
        f32x4 bv[4];
        {
            const float* mu_g2b = mu_g2_in + b * 512; asm volatile("" : "+s"(mu_g2b));
            #pragma unroll
            for (int g = 0; g < 4; ++g)
                bv[g] = ((const f32x4*)mu_g2b)[g * 32 + bq_idx];
        }
        gemm_pf<4, 1, true, true>(Wp_in + WP_WHH0, H1s,
                                  Wp_in + WP_WIH1, 4, bqc, bv, w, lane, acc);
    }
    // epi2: h2 -> H2s (overwrites dead A0; no barrier: S3 reads only H1s)
    #pragma unroll
    for (int mt = 0; mt < 2; ++mt) {
        half4_t hv;
        #pragma unroll
        for (int r = 0; r < 4; ++r) {
            float c2 = sig2(acc[mt][1][r]) * cc[mt][r]
                     + sig2(acc[mt][0][r]) * tanh2(acc[mt][2][r]);
            hv[r] = (_Float16)(sig2(acc[mt][3][r]) * tanh2(c2 * L2E2));
        }
        *(half4_t*)(H2s + swz(mt * 16 + c, w * 32 + q * 8)) = hv;
    }

    // ---- S3: layer1 step1 (A from H1s; bias1 as MFMA C) -------------------
    // Tail-prefetches Wih1 kc=0 AGAIN (S4a uses the same matrix; L2-hot).
    {
        f32x4 bv[4];
        {
            const float* bias1f = bias1f_in; asm volatile("" : "+s"(bias1f));
            #pragma unroll
            for (int g = 0; g < 4; ++g)
                bv[g] = ((const f32x4*)bias1f)[g * 32 + bq_idx];
        }
        gemm_pf<4, 1, true, true>(Wp_in + WP_WIH1, H1s,
                                  Wp_in + WP_WIH1, 4, bqc, bv, w, lane, acc);
    }
    // epi3: h11 -> H11s, cc := layer-1 c1
    #pragma unroll
    for (int mt = 0; mt < 2; ++mt) {
        half4_t hv;
        #pragma unroll
        for (int r = 0; r < 4; ++r) {
            float c1 = sig2(acc[mt][0][r]) * tanh2(acc[mt][2][r]);
            cc[mt][r] = c1;
            hv[r] = (_Float16)(sig2(acc[mt][3][r]) * tanh2(c1 * L2E2));
        }
        *(half4_t*)(H11s + swz(mt * 16 + c, w * 32 + q * 8)) = hv;
    }
    lds_barrier();   // [S3-barrier] H2s + H11s ready; Wih1 kc=0 in flight

    // ---- S4: layer1 step2 (Wih1@H2s + Whh1@H11s; bias1 as MFMA C) ---------
    {
        f32x4 bv[4];
        {
            const float* bias1f = bias1f_in; asm volatile("" : "+s"(bias1f));
            #pragma unroll
            for (int g = 0; g < 4; ++g)
                bv[g] = ((const f32x4*)bias1f)[g * 32 + bq_idx];
        }
        gemm_pf<4, 1, true, true>(Wp_in + WP_WIH1, H2s,
                                  Wp_in + WP_WHH1, 4, bqc, bv, w, lane, acc);
    }
    gemm_pf<4, 1, false, false>(Wp_in + WP_WHH1, H11s,
                                nullptr, 0, bqc, nullptr, w, lane, acc);

    // epilogue: h2_1 -> relu -> dot fc_w; partials straight to L2 atomics
    // (out pre-inited with fc_b in preamble; only this wg touches these 32
    //  rows; the store retires during the intervening vmcnt traffic).
    {
        const float* fc_w = fc_w_in; asm volatile("" : "+s"(fc_w));
        f32x4 fwv = ((const f32x4*)fc_w)[bq_idx];
        #pragma unroll
        for (int mt = 0; mt < 2; ++mt) {
            float v = 0.0f;
            #pragma unroll
            for (int r = 0; r < 4; ++r) {
                float c2 = sig2(acc[mt][1][r]) * cc[mt][r]
                         + sig2(acc[mt][0][r]) * tanh2(acc[mt][2][r]);
                float h  = sig2(acc[mt][3][r]) * tanh2(c2 * L2E2);
                v = fmaf(fmaxf(h, 0.0f), fwv[r], v);
            }
            v += __shfl_xor(v, 16);
            v += __shfl_xor(v, 32);
            if (lane < 16)
                atomicAdd(out + (size_t)wg * 32 + mt * 16 + lane, v);
        }
    }
}

extern "C" void kernel_launch(void* const* d_in, const int* in_sizes, int n_in,
                              void* d_out, int out_size, void* d_ws, size_t ws_size,
                              hipStream_t stream)
{
    const float* x    = (const float*)d_in[0];
    const float* mu   = (const float*)d_in[1];
    const float* Wih0 = (const float*)d_in[2];
    const float* Whh0 = (const float*)d_in[3];
    const float* bih0 = (const float*)d_in[4];
    const float* bhh0 = (const float*)d_in[5];
    const float* Wih1 = (const float*)d_in[6];
    const float* Whh1 = (const float*)d_in[7];
    const float* bih1 = (const float*)d_in[8];
    const float* bhh1 = (const float*)d_in[9];
    const float* fcw  = (const float*)d_in[10];
    const float* fcb  = (const float*)d_in[11];
    float* out = (float*)d_out;

    _Float16* Wp  = (_Float16*)d_ws;
    float* bias0f = (float*)((char*)d_ws + WS_BIAS0);
    float* bias1f = (float*)((char*)d_ws + WS_BIAS1);
    float* mu_g2  = (float*)((char*)d_ws + WS_MUG2);

    hipLaunchKernelGGL(prep_kernel, dim3(241), dim3(256), 0, stream,
                       Wih0, Whh0, Wih1, Whh1, bih0, bhh0, bih1, bhh1, mu,
                       Wp, bias0f, bias1f, mu_g2);
    hipLaunchKernelGGL(lstm_main, dim3(2048), dim3(512), 0, stream,
                       x, Wp, bias0f, bias1f, mu_g2, fcw, fcb, out);
}

// Round 8
// 136.766 us; speedup vs baseline: 3.0371x; 3.0371x over previous
//
#include <hip/hip_runtime.h>

// Forecaster: B=64, S=1024, F=64, H=128. N = B*S = 65536 independent instances.
// R18: structural residency. R17 post-mortem: launch_bounds(512,8) clamped
// VGPR to 32 -> 991MB spill, 383us. NEVER use min-waves clamp here (R12^2).
// Useful datum: R17's occupancy counter read 78% -> the counter is real ->
// R14/R15's ~20% was real: avg ~1 wg/CU resident despite capacity for 2-3.
// 1024 short wgs starve on backfill (ramp/drain). Fix structurally:
//  1. grid 512 = exactly 2 wgs/CU, each wg does 2 tiles (R11 geometry with
//     the R14/R15 pipeline). All wgs resident from t=0; zero backfill.
//  2. Cross-tile prefetch chain: tile0-S4b tail prefetches tile1's Wih0 kc0;
//     tile1 x staged to registers in preamble (+4 VGPR), written to the
//     A0-alias (H2s region) after a post-S4a lgkm barrier (B3); consumed
//     after the tile-1 head barrier (B4).
//  3. f-gate skipped in step-1 gemms (S1/S3): sig(f)*c_prev with c_prev=0 is
//     dead -> 3-gate MFMA set {i,g,o}; 288->264 MFMA/wave-tile, fewer loads.
// Kept: R14 bq prefetch + lgkm-only barriers + bias-as-MFMA-C; A0 aliases
// H2s (LDS 49152); swizzled H tiles; setprio; plain __launch_bounds__(512).

typedef _Float16 half8 __attribute__((ext_vector_type(8)));
typedef _Float16 half4_t __attribute__((ext_vector_type(4)));
typedef float f32x4 __attribute__((ext_vector_type(4)));

#define L2E  1.4426950408889634f
#define L2E2 2.8853900817779268f

#define WP_WIH0 0
#define WP_WHH0 32768
#define WP_WIH1 98304
#define WP_WHH1 163840
#define WS_BIAS0 458752            // bytes
#define WS_BIAS1 (458752 + 2048)
#define WS_MUG2  (458752 + 4096)

// ---------------- merged prep kernel (unchanged) ----------------------------
__global__ void prep_kernel(const float* __restrict__ Wih0,
                            const float* __restrict__ Whh0,
                            const float* __restrict__ Wih1,
                            const float* __restrict__ Whh1,
                            const float* __restrict__ bih0,
                            const float* __restrict__ bhh0,
                            const float* __restrict__ bih1,
                            const float* __restrict__ bhh1,
                            const float* __restrict__ mu,
                            _Float16* __restrict__ Wp,
                            float* __restrict__ bias0f,
                            float* __restrict__ bias1f,
                            float* __restrict__ mu_g2)
{
    int blk = blockIdx.x;
    if (blk >= 113) {                       // ---- mu_g2 part
        int o = (blk - 113) * 256 + threadIdx.x;   // 0..32767
        int b = o >> 9;
        int n = o & 511;
        float s = bih0[n] + bhh0[n];
        const float* m = mu + b * 64;
        const float* wrow = Wih0 + n * 64;
        #pragma unroll 8
        for (int k = 0; k < 64; ++k) s += m[k] * wrow[k];
        float scale = ((n >> 7) == 2) ? L2E2 : L2E;
        mu_g2[o] = s * scale;
        return;
    }
    if (blk == 112) {                       // ---- bias part
        int i = threadIdx.x;
        float sc_hi = (i < 128) ? L2E2 : L2E;
        bias0f[i]       = (bih0[i]       + bhh0[i])       * L2E;
        bias0f[i + 256] = (bih0[i + 256] + bhh0[i + 256]) * sc_hi;
        bias1f[i]       = (bih1[i]       + bhh1[i])       * L2E;
        bias1f[i + 256] = (bih1[i + 256] + bhh1[i + 256]) * sc_hi;
        return;
    }
    // ---- weight pack: [nt][kc][lane][8], c=lane&15 -> n=nt*16+c,
    //      q=lane>>4 -> k = kc*32 + q*8 .. +8  (scaled by gate)
    int gidx = blk * 256 + threadIdx.x;     // 0..28671 groups of 8 halfs
    const float* src; int KC, Kw, local;
    if (gidx < 4096)       { src = Wih0; KC = 2; Kw = 64;  local = gidx; }
    else if (gidx < 12288) { src = Whh0; KC = 4; Kw = 128; local = gidx - 4096; }
    else if (gidx < 20480) { src = Wih1; KC = 4; Kw = 128; local = gidx - 12288; }
    else                   { src = Whh1; KC = 4; Kw = 128; local = gidx - 20480; }
    int lane = local & 63;
    int tmp  = local >> 6;
    int kc   = tmp % KC;
    int nt   = tmp / KC;
    int n  = nt * 16 + (lane & 15);
    int k0 = kc * 32 + (lane >> 4) * 8;
    float scale = ((n >> 7) == 2) ? L2E2 : L2E;
    const float* s = src + n * Kw + k0;
    half8 hv;
    #pragma unroll
    for (int j = 0; j < 8; ++j) hv[j] = (_Float16)(s[j] * scale);
    *(half8*)(Wp + (size_t)gidx * 8) = hv;
}

// ---------------- bare-metal gate math -------------------------------------
__device__ __forceinline__ float sig2(float a) {
    return __builtin_amdgcn_rcpf(1.0f + __builtin_amdgcn_exp2f(-a));
}
__device__ __forceinline__ float tanh2(float a) {
    return fmaf(-2.0f, __builtin_amdgcn_rcpf(1.0f + __builtin_amdgcn_exp2f(a)), 1.0f);
}

// Swizzled byte offset into a [64 rows][256B] H tile (involution; same on
// write and read).
__device__ __forceinline__ int swz(int row, int col) {
    return (row << 8) + (col ^ ((row & 7) << 4));
}

// lgkm-only barrier: orders LDS traffic across the wg WITHOUT draining vmcnt,
// so prefetched global weight loads stay in flight across it (T3/T4).
__device__ __forceinline__ void lds_barrier() {
    asm volatile("s_waitcnt lgkmcnt(0)" ::: "memory");
    __builtin_amdgcn_s_barrier();
    asm volatile("" ::: "memory");
}

// SKIPF: skip gate g=1 (f-gate) — step-1 stages never consume it.
template<bool SKIPF>
__device__ __forceinline__ void load_bq(half8 bq[4], const _Float16* __restrict__ Wq,
                                        int KC, int kc, int w, int lane)
{
    #pragma unroll
    for (int g = 0; g < 4; ++g) {
        if (SKIPF && g == 1) continue;
        bq[g] = *(const half8*)(Wq + (((g * 8 + w) * KC + kc) * 64 + lane) * 8);
    }
}

template<int SRC>   // 0 = A0 (stride 72 halfs), 1 = swizzled H tile
__device__ __forceinline__ void load_a(half8 a[4], const char* base, int kc, int c, int q)
{
    #pragma unroll
    for (int mt = 0; mt < 4; ++mt) {
        if (SRC == 0)
            a[mt] = *(const half8*)((const _Float16*)base + (mt * 16 + c) * 72 + kc * 32 + q * 8);
        else
            a[mt] = *(const half8*)(base + swz(mt * 16 + c, kc * 64 + q * 16));
    }
}

// One gemm stage, 1-deep bq double-buffer. SKIPF: this stage uses gates
// {0,2,3} only. NSKIPF: the NEXT stage's gate-set (for the tail prefetch).
// On entry bqc holds this stage's kc=0 quads; on exit (PF) the next stage's.
// FIRST: bv[g] is the MFMA C operand at kc=0 (bias init without v_movs).
template<int KC, int SRC, bool PF, bool FIRST, bool SKIPF, bool NSKIPF>
__device__ __forceinline__ void gemm_pf(const _Float16* __restrict__ Wq,
                                        const char* Abase,
                                        const _Float16* __restrict__ Wnext, int KCnext,
                                        half8 bqc[4], const f32x4 bv[4],
                                        int w, int lane, f32x4 acc[4][4])
{
    const int c = lane & 15, q = lane >> 4;
    #pragma unroll
    for (int kc = 0; kc < KC; ++kc) {
        half8 bqn[4];
        if (kc + 1 < KC)  load_bq<SKIPF>(bqn, Wq, KC, kc + 1, w, lane);
        else if (PF)      load_bq<NSKIPF>(bqn, Wnext, KCnext, 0, w, lane);
        half8 a[4];
        load_a<SRC>(a, Abase, kc, c, q);
        __builtin_amdgcn_s_setprio(1);
        #pragma unroll
        for (int mt = 0; mt < 4; ++mt)
            #pragma unroll
            for (int g = 0; g < 4; ++g) {
                if (SKIPF && g == 1) continue;
                f32x4 cin = (FIRST && kc == 0) ? bv[g] : acc[mt][g];
                acc[mt][g] = __builtin_amdgcn_mfma_f32_16x16x32_f16(bqc[g], a[mt], cin, 0, 0, 0);
            }
        __builtin_amdgcn_s_setprio(0);
        if (kc + 1 < KC) {
            #pragma unroll
            for (int g = 0; g < 4; ++g)
                if (!(SKIPF && g == 1)) bqc[g] = bqn[g];
        } else if (PF) {
            #pragma unroll
            for (int g = 0; g < 4; ++g)
                if (!(NSKIPF && g == 1)) bqc[g] = bqn[g];
        }
    }
}

__global__ __launch_bounds__(512) void lstm_main(
    const float* __restrict__ x, const _Float16* __restrict__ Wp_in,
    const float* __restrict__ bias0f_in, const float* __restrict__ bias1f_in,
    const float* __restrict__ mu_g2_in, const float* __restrict__ fc_w_in,
    const float* __restrict__ fc_b_in, float* __restrict__ out)
{
    // LDS 49152 B:
    //  [0, 16384)       H1s   (swizzled [64][256B])
    //  [16384, 32768)   H2s   -- ALSO hosts A0 (64 x 72 halfs = 9216 B).
    //       A0 lifetime per tile: [staging, S1-gemm]; dead at the S1-barrier
    //       (lgkmcnt(0) drains its ds_reads); H2s written by epi2 after it.
    //       Tile-1 restaging: after B3 (post-S4a lgkm barrier -> all waves'
    //       H2s reads done), consumed after B4 (tile-1 head barrier).
    //  [32768, 49152)   H11s
    __shared__ __align__(16) char smem[49152];
    char* H1s  = smem;
    char* H2s  = smem + 16384;
    char* H11s = smem + 32768;
    _Float16* A0 = (_Float16*)(smem + 16384);    // alias of H2s region

    const int t = threadIdx.x;
    const int w = t >> 6, lane = t & 63, c = lane & 15, q = lane >> 4;
    const int wg = blockIdx.x;                   // 512 wgs x 2 tiles x 64 rows
    const int b = wg >> 3;                       // 8 wgs (1024 rows) per batch
    const int bq_idx = w * 4 + q;                // float4 index of (w,q) slice

    // ---- prefetch S1(tile0) weights {i,g,o} with maximum lead -------------
    half8 bqc[4];
    load_bq<true>(bqc, Wp_in + WP_WIH0, 2, 0, w, lane);

    // ---- preamble: tile0 x -> A0; tile1 x -> ax1 regs; init out (128 rows)
    half8 ax1;
    {
        const float* xp = x + (size_t)wg * 8192 + t * 8;
        float4 u0 = ((const float4*)xp)[0];
        float4 u1 = ((const float4*)xp)[1];
        half8 hv;
        hv[0] = (_Float16)u0.x; hv[1] = (_Float16)u0.y;
        hv[2] = (_Float16)u0.z; hv[3] = (_Float16)u0.w;
        hv[4] = (_Float16)u1.x; hv[5] = (_Float16)u1.y;
        hv[6] = (_Float16)u1.z; hv[7] = (_Float16)u1.w;
        *(half8*)(A0 + (t >> 3) * 72 + (t & 7) * 8) = hv;
        const float* xp1 = x + (size_t)wg * 8192 + 4096 + t * 8;
        float4 v0 = ((const float4*)xp1)[0];
        float4 v1 = ((const float4*)xp1)[1];
        ax1[0] = (_Float16)v0.x; ax1[1] = (_Float16)v0.y;
        ax1[2] = (_Float16)v0.z; ax1[3] = (_Float16)v0.w;
        ax1[4] = (_Float16)v1.x; ax1[5] = (_Float16)v1.y;
        ax1[6] = (_Float16)v1.z; ax1[7] = (_Float16)v1.w;
        if (t < 128) out[(size_t)wg * 128 + t] = fc_b_in[0];
    }
    lds_barrier();   // A0(t0) visible; out-init retires long before atomics

    f32x4 acc[4][4];
    float cc[4][4];

    #pragma unroll
    for (int tile = 0; tile < 2; ++tile) {
        if (tile == 1) lds_barrier();   // [B4] A0(t1) visible to all waves

        // ---- S1: layer0 step1 (A from A0; bias0 as C; gates {i,g,o}) ------
        {
            f32x4 bv[4];
            {
                const float* bias0f = bias0f_in; asm volatile("" : "+s"(bias0f));
                #pragma unroll
                for (int g = 0; g < 4; ++g)
                    if (g != 1) bv[g] = ((const f32x4*)bias0f)[g * 32 + bq_idx];
            }
            gemm_pf<2, 0, true, true, true, false>(
                Wp_in + WP_WIH0, (const char*)A0,
                Wp_in + WP_WHH0, 4, bqc, bv, w, lane, acc);
        }
        #pragma unroll
        for (int mt = 0; mt < 4; ++mt) {
            half4_t hv;
            #pragma unroll
            for (int r = 0; r < 4; ++r) {
                float c1 = sig2(acc[mt][0][r]) * tanh2(acc[mt][2][r]);
                cc[mt][r] = c1;
                hv[r] = (_Float16)(sig2(acc[mt][3][r]) * tanh2(c1 * L2E2));
            }
            *(half4_t*)(H1s + swz(mt * 16 + c, w * 32 + q * 8)) = hv;
        }
        lds_barrier();   // [B1] H1s ready; A0 dead; Whh0 kc=0 in flight

        // ---- S2: layer0 step2 (A from H1s; mu_g2 as C; all gates) ---------
        // Tail prefetches Wih1 kc=0 for S3 (gates {i,g,o}).
        {
            f32x4 bv[4];
            {
                const float* mu_g2b = mu_g2_in + b * 512; asm volatile("" : "+s"(mu_g2b));
                #pragma unroll
                for (int g = 0; g < 4; ++g)
                    bv[g] = ((const f32x4*)mu_g2b)[g * 32 + bq_idx];
            }
            gemm_pf<4, 1, true, true, false, true>(
                Wp_in + WP_WHH0, H1s,
                Wp_in + WP_WIH1, 4, bqc, bv, w, lane, acc);
        }
        // epi2: h2 -> H2s (overwrites dead A0; no barrier: S3 reads only H1s)
        #pragma unroll
        for (int mt = 0; mt < 4; ++mt) {
            half4_t hv;
            #pragma unroll
            for (int r = 0; r < 4; ++r) {
                float c2 = sig2(acc[mt][1][r]) * cc[mt][r]
                         + sig2(acc[mt][0][r]) * tanh2(acc[mt][2][r]);
                hv[r] = (_Float16)(sig2(acc[mt][3][r]) * tanh2(c2 * L2E2));
            }
            *(half4_t*)(H2s + swz(mt * 16 + c, w * 32 + q * 8)) = hv;
        }

        // ---- S3: layer1 step1 (A from H1s; bias1 as C; gates {i,g,o}) -----
        // Tail prefetches Wih1 kc=0 for S4a (all gates; L2-hot).
        {
            f32x4 bv[4];
            {
                const float* bias1f = bias1f_in; asm volatile("" : "+s"(bias1f));
                #pragma unroll
                for (int g = 0; g < 4; ++g)
                    if (g != 1) bv[g] = ((const f32x4*)bias1f)[g * 32 + bq_idx];
            }
            gemm_pf<4, 1, true, true, true, false>(
                Wp_in + WP_WIH1, H1s,
                Wp_in + WP_WIH1, 4, bqc, bv, w, lane, acc);
        }
        // epi3: h11 -> H11s, cc := layer-1 c1
        #pragma unroll
        for (int mt = 0; mt < 4; ++mt) {
            half4_t hv;
            #pragma unroll
            for (int r = 0; r < 4; ++r) {
                float c1 = sig2(acc[mt][0][r]) * tanh2(acc[mt][2][r]);
                cc[mt][r] = c1;
                hv[r] = (_Float16)(sig2(acc[mt][3][r]) * tanh2(c1 * L2E2));
            }
            *(half4_t*)(H11s + swz(mt * 16 + c, w * 32 + q * 8)) = hv;
        }
        lds_barrier();   // [B2] H2s + H11s ready; Wih1 kc=0 in flight

        // ---- S4a: Wih1 @ H2s (bias1 as C; all gates) ----------------------
        {
            f32x4 bv[4];
            {
                const float* bias1f = bias1f_in; asm volatile("" : "+s"(bias1f));
                #pragma unroll
                for (int g = 0; g < 4; ++g)
                    bv[g] = ((const f32x4*)bias1f)[g * 32 + bq_idx];
            }
            gemm_pf<4, 1, true, true, false, false>(
                Wp_in + WP_WIH1, H2s,
                Wp_in + WP_WHH1, 4, bqc, bv, w, lane, acc);
        }

        if (tile == 0) {
            lds_barrier();   // [B3] all waves' H2s reads (S4a) done
            // restage tile-1 x into the A0 alias; consumed after B4
            *(half8*)(A0 + (t >> 3) * 72 + (t & 7) * 8) = ax1;
            // ---- S4b: Whh1 @ H11s; tail prefetches tile-1's Wih0 kc=0 -----
            gemm_pf<4, 1, true, false, false, true>(
                Wp_in + WP_WHH1, H11s,
                Wp_in + WP_WIH0, 2, bqc, nullptr, w, lane, acc);
        } else {
            gemm_pf<4, 1, false, false, false, false>(
                Wp_in + WP_WHH1, H11s,
                nullptr, 0, bqc, nullptr, w, lane, acc);
        }

        // epilogue: h2_1 -> relu -> dot fc_w; partials to L2 atomics
        {
            const float* fc_w = fc_w_in; asm volatile("" : "+s"(fc_w));
            f32x4 fwv = ((const f32x4*)fc_w)[bq_idx];
            #pragma unroll
            for (int mt = 0; mt < 4; ++mt) {
                float v = 0.0f;
                #pragma unroll
                for (int r = 0; r < 4; ++r) {
                    float c2 = sig2(acc[mt][1][r]) * cc[mt][r]
                             + sig2(acc[mt][0][r]) * tanh2(acc[mt][2][r]);
                    float h  = sig2(acc[mt][3][r]) * tanh2(c2 * L2E2);
                    v = fmaf(fmaxf(h, 0.0f), fwv[r], v);
                }
                v += __shfl_xor(v, 16);
                v += __shfl_xor(v, 32);
                if (lane < 16)
                    atomicAdd(out + (size_t)wg * 128 + tile * 64 + mt * 16 + lane, v);
            }
        }
    }
}

extern "C" void kernel_launch(void* const* d_in, const int* in_sizes, int n_in,
                              void* d_out, int out_size, void* d_ws, size_t ws_size,
                              hipStream_t stream)
{
    const float* x    = (const float*)d_in[0];
    const float* mu   = (const float*)d_in[1];
    const float* Wih0 = (const float*)d_in[2];
    const float* Whh0 = (const float*)d_in[3];
    const float* bih0 = (const float*)d_in[4];
    const float* bhh0 = (const float*)d_in[5];
    const float* Wih1 = (const float*)d_in[6];
    const float* Whh1 = (const float*)d_in[7];
    const float* bih1 = (const float*)d_in[8];
    const float* bhh1 = (const float*)d_in[9];
    const float* fcw  = (const float*)d_in[10];
    const float* fcb  = (const float*)d_in[11];
    float* out = (float*)d_out;

    _Float16* Wp  = (_Float16*)d_ws;
    float* bias0f = (float*)((char*)d_ws + WS_BIAS0);
    float* bias1f = (float*)((char*)d_ws + WS_BIAS1);
    float* mu_g2  = (float*)((char*)d_ws + WS_MUG2);

    hipLaunchKernelGGL(prep_kernel, dim3(241), dim3(256), 0, stream,
                       Wih0, Whh0, Wih1, Whh1, bih0, bhh0, bih1, bhh1, mu,
                       Wp, bias0f, bias1f, mu_g2);
    hipLaunchKernelGGL(lstm_main, dim3(512), dim3(512), 0, stream,
                       x, Wp, bias0f, bias1f, mu_g2, fcw, fcb, out);
}

// Round 9
// 132.731 us; speedup vs baseline: 3.1294x; 1.0304x over previous
//
#include <hip/hip_runtime.h>

// Forecaster: B=64, S=1024, F=64, H=128. N = B*S = 65536 independent instances.
// R19: VALU-volume attack. R18 post-mortem: structural residency (512 wgs
// all resident t=0) did NOT move occupancy/busy counters -> the ~20%
// occupancy reading is not backfill; scheduling levers are exhausted
// (R14 pipeline was the only win; R15/R16/R18 null-to-negative; 2-tile
// barriers cost ~2us). Revert to R15 geometry; cut work instead:
//  1. Fused sig(x)*tanh(y) = (e-1)*rcp((1+d)(1+e)), d=exp2(-x), e=exp2(y):
//     3 trans per pair instead of 4. ~576 -> ~448 trans/thread (-22% of
//     the dominant VALU consumer). Same bias/weight pre-scaling (L2E/L2E2).
//  2. f-gate skip in S1/S3 (step-1: c_prev=0 -> f dead): 3-gate MFMA set,
//     -24 MFMA, fewer weight/bias loads (R18 idea, unbundled from 2-tile).
// Kept: R15 geometry (grid 1024, 64-row wgs, 1 tile); R14 bq prefetch +
// lgkm-only barriers + bias-as-MFMA-C; A0 aliases H2s (LDS 49152);
// swizzled H tiles; setprio; plain __launch_bounds__(512).
// NEVER: min-waves clamp (R12/R17: VGPR clamp -> spill disaster).

typedef _Float16 half8 __attribute__((ext_vector_type(8)));
typedef _Float16 half4_t __attribute__((ext_vector_type(4)));
typedef float f32x4 __attribute__((ext_vector_type(4)));

#define L2E  1.4426950408889634f
#define L2E2 2.8853900817779268f

#define WP_WIH0 0
#define WP_WHH0 32768
#define WP_WIH1 98304
#define WP_WHH1 163840
#define WS_BIAS0 458752            // bytes
#define WS_BIAS1 (458752 + 2048)
#define WS_MUG2  (458752 + 4096)

// ---------------- merged prep kernel (unchanged) ----------------------------
__global__ void prep_kernel(const float* __restrict__ Wih0,
                            const float* __restrict__ Whh0,
                            const float* __restrict__ Wih1,
                            const float* __restrict__ Whh1,
                            const float* __restrict__ bih0,
                            const float* __restrict__ bhh0,
                            const float* __restrict__ bih1,
                            const float* __restrict__ bhh1,
                            const float* __restrict__ mu,
                            _Float16* __restrict__ Wp,
                            float* __restrict__ bias0f,
                            float* __restrict__ bias1f,
                            float* __restrict__ mu_g2)
{
    int blk = blockIdx.x;
    if (blk >= 113) {                       // ---- mu_g2 part
        int o = (blk - 113) * 256 + threadIdx.x;   // 0..32767
        int b = o >> 9;
        int n = o & 511;
        float s = bih0[n] + bhh0[n];
        const float* m = mu + b * 64;
        const float* wrow = Wih0 + n * 64;
        #pragma unroll 8
        for (int k = 0; k < 64; ++k) s += m[k] * wrow[k];
        float scale = ((n >> 7) == 2) ? L2E2 : L2E;
        mu_g2[o] = s * scale;
        return;
    }
    if (blk == 112) {                       // ---- bias part
        int i = threadIdx.x;
        float sc_hi = (i < 128) ? L2E2 : L2E;
        bias0f[i]       = (bih0[i]       + bhh0[i])       * L2E;
        bias0f[i + 256] = (bih0[i + 256] + bhh0[i + 256]) * sc_hi;
        bias1f[i]       = (bih1[i]       + bhh1[i])       * L2E;
        bias1f[i + 256] = (bih1[i + 256] + bhh1[i + 256]) * sc_hi;
        return;
    }
    // ---- weight pack: [nt][kc][lane][8], c=lane&15 -> n=nt*16+c,
    //      q=lane>>4 -> k = kc*32 + q*8 .. +8  (scaled by gate)
    int gidx = blk * 256 + threadIdx.x;     // 0..28671 groups of 8 halfs
    const float* src; int KC, Kw, local;
    if (gidx < 4096)       { src = Wih0; KC = 2; Kw = 64;  local = gidx; }
    else if (gidx < 12288) { src = Whh0; KC = 4; Kw = 128; local = gidx - 4096; }
    else if (gidx < 20480) { src = Wih1; KC = 4; Kw = 128; local = gidx - 12288; }
    else                   { src = Whh1; KC = 4; Kw = 128; local = gidx - 20480; }
    int lane = local & 63;
    int tmp  = local >> 6;
    int kc   = tmp % KC;
    int nt   = tmp / KC;
    int n  = nt * 16 + (lane & 15);
    int k0 = kc * 32 + (lane >> 4) * 8;
    float scale = ((n >> 7) == 2) ? L2E2 : L2E;
    const float* s = src + n * Kw + k0;
    half8 hv;
    #pragma unroll
    for (int j = 0; j < 8; ++j) hv[j] = (_Float16)(s[j] * scale);
    *(half8*)(Wp + (size_t)gidx * 8) = hv;
}

// ---------------- bare-metal gate math -------------------------------------
__device__ __forceinline__ float sig2(float a) {
    return __builtin_amdgcn_rcpf(1.0f + __builtin_amdgcn_exp2f(-a));
}
// Fused sig(x̂)·tanh(ŷ): x̂ = x·L2E (sigmoid arg), ŷ = y·L2E2 (tanh arg).
//   sig·tanh = (e-1) / ((1+d)(1+e)),  d = exp2(-x̂), e = exp2(ŷ)
// 3 trans (2 exp2 + 1 rcp) vs 4 in the separate forms.
__device__ __forceinline__ float sigtanh(float xs, float yt) {
    float d = __builtin_amdgcn_exp2f(-xs);
    float e = __builtin_amdgcn_exp2f(yt);
    return (e - 1.0f) * __builtin_amdgcn_rcpf((1.0f + d) * (1.0f + e));
}

// Swizzled byte offset into a [64 rows][256B] H tile (involution; same on
// write and read).
__device__ __forceinline__ int swz(int row, int col) {
    return (row << 8) + (col ^ ((row & 7) << 4));
}

// lgkm-only barrier: orders LDS traffic across the wg WITHOUT draining vmcnt,
// so prefetched global weight loads stay in flight across it (T3/T4).
__device__ __forceinline__ void lds_barrier() {
    asm volatile("s_waitcnt lgkmcnt(0)" ::: "memory");
    __builtin_amdgcn_s_barrier();
    asm volatile("" ::: "memory");
}

// SKIPF: skip gate g=1 (f-gate) — step-1 stages never consume it.
template<bool SKIPF>
__device__ __forceinline__ void load_bq(half8 bq[4], const _Float16* __restrict__ Wq,
                                        int KC, int kc, int w, int lane)
{
    #pragma unroll
    for (int g = 0; g < 4; ++g) {
        if (SKIPF && g == 1) continue;
        bq[g] = *(const half8*)(Wq + (((g * 8 + w) * KC + kc) * 64 + lane) * 8);
    }
}

template<int SRC>   // 0 = A0 (stride 72 halfs), 1 = swizzled H tile
__device__ __forceinline__ void load_a(half8 a[4], const char* base, int kc, int c, int q)
{
    #pragma unroll
    for (int mt = 0; mt < 4; ++mt) {
        if (SRC == 0)
            a[mt] = *(const half8*)((const _Float16*)base + (mt * 16 + c) * 72 + kc * 32 + q * 8);
        else
            a[mt] = *(const half8*)(base + swz(mt * 16 + c, kc * 64 + q * 16));
    }
}

// One gemm stage, 1-deep bq double-buffer. SKIPF: this stage uses gates
// {0,2,3} only. NSKIPF: the NEXT stage's gate-set (for the tail prefetch).
// On entry bqc holds this stage's kc=0 quads; on exit (PF) the next stage's.
// FIRST: bv[g] is the MFMA C operand at kc=0 (bias init without v_movs).
template<int KC, int SRC, bool PF, bool FIRST, bool SKIPF, bool NSKIPF>
__device__ __forceinline__ void gemm_pf(const _Float16* __restrict__ Wq,
                                        const char* Abase,
                                        const _Float16* __restrict__ Wnext, int KCnext,
                                        half8 bqc[4], const f32x4 bv[4],
                                        int w, int lane, f32x4 acc[4][4])
{
    const int c = lane & 15, q = lane >> 4;
    #pragma unroll
    for (int kc = 0; kc < KC; ++kc) {
        half8 bqn[4];
        if (kc + 1 < KC)  load_bq<SKIPF>(bqn, Wq, KC, kc + 1, w, lane);
        else if (PF)      load_bq<NSKIPF>(bqn, Wnext, KCnext, 0, w, lane);
        half8 a[4];
        load_a<SRC>(a, Abase, kc, c, q);
        __builtin_amdgcn_s_setprio(1);
        #pragma unroll
        for (int mt = 0; mt < 4; ++mt)
            #pragma unroll
            for (int g = 0; g < 4; ++g) {
                if (SKIPF && g == 1) continue;
                f32x4 cin = (FIRST && kc == 0) ? bv[g] : acc[mt][g];
                acc[mt][g] = __builtin_amdgcn_mfma_f32_16x16x32_f16(bqc[g], a[mt], cin, 0, 0, 0);
            }
        __builtin_amdgcn_s_setprio(0);
        if (kc + 1 < KC) {
            #pragma unroll
            for (int g = 0; g < 4; ++g)
                if (!(SKIPF && g == 1)) bqc[g] = bqn[g];
        } else if (PF) {
            #pragma unroll
            for (int g = 0; g < 4; ++g)
                if (!(NSKIPF && g == 1)) bqc[g] = bqn[g];
        }
    }
}

__global__ __launch_bounds__(512) void lstm_main(
    const float* __restrict__ x, const _Float16* __restrict__ Wp_in,
    const float* __restrict__ bias0f_in, const float* __restrict__ bias1f_in,
    const float* __restrict__ mu_g2_in, const float* __restrict__ fc_w_in,
    const float* __restrict__ fc_b_in, float* __restrict__ out)
{
    // LDS 49152 B:
    //  [0, 16384)       H1s   (swizzled [64][256B])
    //  [16384, 32768)   H2s   -- ALSO hosts A0 (64 x 72 halfs = 9216 B):
    //                      A0 dead at S1-barrier (lgkmcnt(0) drains its
    //                      ds_reads); H2s first written in epi2 after it.
    //  [32768, 49152)   H11s
    __shared__ __align__(16) char smem[49152];
    char* H1s  = smem;
    char* H2s  = smem + 16384;
    char* H11s = smem + 32768;
    _Float16* A0 = (_Float16*)(smem + 16384);    // alias of H2s region

    const int t = threadIdx.x;
    const int w = t >> 6, lane = t & 63, c = lane & 15, q = lane >> 4;
    const int wg = blockIdx.x;                   // 1024 wgs x 64 rows
    const int b = wg >> 4;                       // 16 wgs (1024 rows) per batch
    const int bq_idx = w * 4 + q;                // float4 index of (w,q) slice

    // ---- prefetch S1 kc=0 weights {i,g,o} with maximum lead ---------------
    half8 bqc[4];
    load_bq<true>(bqc, Wp_in + WP_WIH0, 2, 0, w, lane);

    // ---- preamble: stage x tile into A0 (coalesced); init out rows --------
    {
        const float* xp = x + (size_t)wg * 4096 + t * 8;
        float4 u0 = ((const float4*)xp)[0];
        float4 u1 = ((const float4*)xp)[1];
        half8 hv;
        hv[0] = (_Float16)u0.x; hv[1] = (_Float16)u0.y;
        hv[2] = (_Float16)u0.z; hv[3] = (_Float16)u0.w;
        hv[4] = (_Float16)u1.x; hv[5] = (_Float16)u1.y;
        hv[6] = (_Float16)u1.z; hv[7] = (_Float16)u1.w;
        *(half8*)(A0 + (t >> 3) * 72 + (t & 7) * 8) = hv;
        if (t < 64) out[(size_t)wg * 64 + t] = fc_b_in[0];
    }
    lds_barrier();   // A0 visible (lgkm); weight prefetch still in flight

    f32x4 acc[4][4];
    float cc[4][4];

    // ---- S1: layer0 step1 (A from A0; bias0 as C; gates {i,g,o}) ----------
    {
        f32x4 bv[4];
        {
            const float* bias0f = bias0f_in; asm volatile("" : "+s"(bias0f));
            #pragma unroll
            for (int g = 0; g < 4; ++g)
                if (g != 1) bv[g] = ((const f32x4*)bias0f)[g * 32 + bq_idx];
        }
        gemm_pf<2, 0, true, true, true, false>(
            Wp_in + WP_WIH0, (const char*)A0,
            Wp_in + WP_WHH0, 4, bqc, bv, w, lane, acc);
    }
    // epi1: c1 = sig(i)tanh(g) [fused]; h1 = sig(o)tanh(c1) [fused]
    #pragma unroll
    for (int mt = 0; mt < 4; ++mt) {
        half4_t hv;
        #pragma unroll
        for (int r = 0; r < 4; ++r) {
            float c1 = sigtanh(acc[mt][0][r], acc[mt][2][r]);
            cc[mt][r] = c1;
            hv[r] = (_Float16)sigtanh(acc[mt][3][r], c1 * L2E2);
        }
        *(half4_t*)(H1s + swz(mt * 16 + c, w * 32 + q * 8)) = hv;
    }
    lds_barrier();   // [S1-barrier] H1s ready; A0 dead; Whh0 kc=0 in flight

    // ---- S2: layer0 step2 (A from H1s; mu_g2 as C; all gates) -------------
    // Tail prefetches Wih1 kc=0 for S3 (gates {i,g,o}).
    {
        f32x4 bv[4];
        {
            const float* mu_g2b = mu_g2_in + b * 512; asm volatile("" : "+s"(mu_g2b));
            #pragma unroll
            for (int g = 0; g < 4; ++g)
                bv[g] = ((const f32x4*)mu_g2b)[g * 32 + bq_idx];
        }
        gemm_pf<4, 1, true, true, false, true>(
            Wp_in + WP_WHH0, H1s,
            Wp_in + WP_WIH1, 4, bqc, bv, w, lane, acc);
    }
    // epi2: c2 = sig(f)*c1 + sig(i)tanh(g) [fused]; h2 = sig(o)tanh(c2) [fused]
    #pragma unroll
    for (int mt = 0; mt < 4; ++mt) {
        half4_t hv;
        #pragma unroll
        for (int r = 0; r < 4; ++r) {
            float c2 = sig2(acc[mt][1][r]) * cc[mt][r]
                     + sigtanh(acc[mt][0][r], acc[mt][2][r]);
            hv[r] = (_Float16)sigtanh(acc[mt][3][r], c2 * L2E2);
        }
        *(half4_t*)(H2s + swz(mt * 16 + c, w * 32 + q * 8)) = hv;
    }

    // ---- S3: layer1 step1 (A from H1s; bias1 as C; gates {i,g,o}) ---------
    // Tail prefetches Wih1 kc=0 for S4a (all gates; L2-hot).
    {
        f32x4 bv[4];
        {
            const float* bias1f = bias1f_in; asm volatile("" : "+s"(bias1f));
            #pragma unroll
            for (int g = 0; g < 4; ++g)
                if (g != 1) bv[g] = ((const f32x4*)bias1f)[g * 32 + bq_idx];
        }
        gemm_pf<4, 1, true, true, true, false>(
            Wp_in + WP_WIH1, H1s,
            Wp_in + WP_WIH1, 4, bqc, bv, w, lane, acc);
    }
    // epi3: h11 -> H11s, cc := layer-1 c1 (both fused)
    #pragma unroll
    for (int mt = 0; mt < 4; ++mt) {
        half4_t hv;
        #pragma unroll
        for (int r = 0; r < 4; ++r) {
            float c1 = sigtanh(acc[mt][0][r], acc[mt][2][r]);
            cc[mt][r] = c1;
            hv[r] = (_Float16)sigtanh(acc[mt][3][r], c1 * L2E2);
        }
        *(half4_t*)(H11s + swz(mt * 16 + c, w * 32 + q * 8)) = hv;
    }
    lds_barrier();   // [S3-barrier] H2s + H11s ready; Wih1 kc=0 in flight

    // ---- S4: layer1 step2 (Wih1@H2s + Whh1@H11s; bias1 as C; all gates) ---
    {
        f32x4 bv[4];
        {
            const float* bias1f = bias1f_in; asm volatile("" : "+s"(bias1f));
            #pragma unroll
            for (int g = 0; g < 4; ++g)
                bv[g] = ((const f32x4*)bias1f)[g * 32 + bq_idx];
        }
        gemm_pf<4, 1, true, true, false, false>(
            Wp_in + WP_WIH1, H2s,
            Wp_in + WP_WHH1, 4, bqc, bv, w, lane, acc);
    }
    gemm_pf<4, 1, false, false, false, false>(
        Wp_in + WP_WHH1, H11s,
        nullptr, 0, bqc, nullptr, w, lane, acc);

    // epilogue: h2_1 -> relu -> dot fc_w; partials straight to L2 atomics
    // (out pre-inited with fc_b in preamble; only this wg touches these 64
    //  rows; the store retires during the intervening vmcnt traffic).
    {
        const float* fc_w = fc_w_in; asm volatile("" : "+s"(fc_w));
        f32x4 fwv = ((const f32x4*)fc_w)[bq_idx];
        #pragma unroll
        for (int mt = 0; mt < 4; ++mt) {
            float v = 0.0f;
            #pragma unroll
            for (int r = 0; r < 4; ++r) {
                float c2 = sig2(acc[mt][1][r]) * cc[mt][r]
                         + sigtanh(acc[mt][0][r], acc[mt][2][r]);
                float h  = sigtanh(acc[mt][3][r], c2 * L2E2);
                v = fmaf(fmaxf(h, 0.0f), fwv[r], v);
            }
            v += __shfl_xor(v, 16);
            v += __shfl_xor(v, 32);
            if (lane < 16)
                atomicAdd(out + (size_t)wg * 64 + mt * 16 + lane, v);
        }
    }
}

extern "C" void kernel_launch(void* const* d_in, const int* in_sizes, int n_in,
                              void* d_out, int out_size, void* d_ws, size_t ws_size,
                              hipStream_t stream)
{
    const float* x    = (const float*)d_in[0];
    const float* mu   = (const float*)d_in[1];
    const float* Wih0 = (const float*)d_in[2];
    const float* Whh0 = (const float*)d_in[3];
    const float* bih0 = (const float*)d_in[4];
    const float* bhh0 = (const float*)d_in[5];
    const float* Wih1 = (const float*)d_in[6];
    const float* Whh1 = (const float*)d_in[7];
    const float* bih1 = (const float*)d_in[8];
    const float* bhh1 = (const float*)d_in[9];
    const float* fcw  = (const float*)d_in[10];
    const float* fcb  = (const float*)d_in[11];
    float* out = (float*)d_out;

    _Float16* Wp  = (_Float16*)d_ws;
    float* bias0f = (float*)((char*)d_ws + WS_BIAS0);
    float* bias1f = (float*)((char*)d_ws + WS_BIAS1);
    float* mu_g2  = (float*)((char*)d_ws + WS_MUG2);

    hipLaunchKernelGGL(prep_kernel, dim3(241), dim3(256), 0, stream,
                       Wih0, Whh0, Wih1, Whh1, bih0, bhh0, bih1, bhh1, mu,
                       Wp, bias0f, bias1f, mu_g2);
    hipLaunchKernelGGL(lstm_main, dim3(1024), dim3(512), 0, stream,
                       x, Wp, bias0f, bias1f, mu_g2, fcw, fcb, out);
}